// Round 2
// baseline (1029.415 us; speedup 1.0000x reference)
//
#include <hip/hip_runtime.h>
#include <hip/hip_fp16.h>
#include <stdint.h>

#define BB 256
#define TT 511
#define VV 128
#define HH 256
#define G4 1024   // 4*H

typedef _Float16 h2_t __attribute__((ext_vector_type(2)));

__device__ __forceinline__ float fdot2(uint32_t a, uint32_t b, float c) {
  return __builtin_amdgcn_fdot2(__builtin_bit_cast(h2_t, a),
                                __builtin_bit_cast(h2_t, b), c, false);
}

__device__ __forceinline__ uint32_t pack2(float a, float b) {
  __half ha = __float2half(a), hb = __float2half(b);
  return (uint32_t)__half_as_ushort(ha) | ((uint32_t)__half_as_ushort(hb) << 16);
}

// ---------------- prep kernels ----------------

__global__ __launch_bounds__(1024) void prep_ctx_k(
    const int* __restrict__ rhythm, const int* __restrict__ meter, const int* __restrict__ keyi,
    const float* __restrict__ er, const float* __restrict__ em, const float* __restrict__ ek,
    const float* __restrict__ W, const float* __restrict__ bias, float* __restrict__ ctxW) {
  int b = blockIdx.x, j = threadIdx.x;
  int r = rhythm[b], m = meter[b], k = keyi[b];
  float acc = bias[j];
#pragma unroll
  for (int e = 0; e < 16; e++) acc += er[r*16+e] * W[(0+e)*G4 + j];
#pragma unroll
  for (int e = 0; e < 16; e++) acc += em[m*16+e] * W[(16+e)*G4 + j];
#pragma unroll
  for (int e = 0; e < 16; e++) acc += ek[k*16+e] * W[(32+e)*G4 + j];
  ctxW[b*G4 + j] = acc;
}

__global__ __launch_bounds__(1024) void prep_tune_k(
    const float* __restrict__ et, const float* __restrict__ W, float* __restrict__ tuneW) {
  int v = blockIdx.x, j = threadIdx.x;
  float acc = 0.f;
#pragma unroll
  for (int e = 0; e < 32; e++) acc += et[v*32+e] * W[(48+e)*G4 + j];
  tuneW[v*G4 + j] = acc;
}

__global__ __launch_bounds__(1024) void prep_U_k(
    const float* __restrict__ U, uint32_t* __restrict__ Up) {
  int kk = blockIdx.x, j = threadIdx.x;   // kk in [0,128): packed k-pair index
  Up[kk*G4 + j] = pack2(U[(2*kk)*G4 + j], U[(2*kk+1)*G4 + j]);
}

__global__ __launch_bounds__(128) void prep_Wd_k(
    const float* __restrict__ Wd, uint32_t* __restrict__ Wdp) {
  int kp = blockIdx.x, v = threadIdx.x;   // kp in [0,128)
  Wdp[kp*VV + v] = pack2(Wd[(2*kp)*VV + v], Wd[(2*kp+1)*VV + v]);
}

// ---------------- recurrent kernel ----------------
// 2-way K-split: waves 0-3 own kp 0..63, waves 4-7 own kp 64..127.
// Each thread owns 4 consecutive columns (c = 4q..4q+3).
// Per slice of 64 kp: 54 kp in VGPRs (216 regs), 10 kp in LDS.
// h broadcast via lane-spread ds_read_b32 + v_readlane -> SGPR operand of v_dot2.

#define NT 512
#define KREG 54
#define KLDS 10
#define ULDS_ROWS (2*KLDS)
// u32 layout: Ulds[20*1024] | zpart[2*1024 f32] | ctx[1024 f32] | hbuf[128] | tlds[512]
#define OFF_ZPART (ULDS_ROWS*G4)
#define OFF_CTX   (OFF_ZPART + 2*G4)
#define OFF_HBUF  (OFF_CTX + G4)
#define OFF_TLDS  (OFF_HBUF + 128)
#define SMEM_U32  (OFF_TLDS + 512)
#define SMEM_BYTES (SMEM_U32*4)   // 96,768 B

__global__ __launch_bounds__(NT) void lstm_rec_k(
    const int* __restrict__ tune, const int* __restrict__ tlen,
    const uint32_t* __restrict__ Up, const float* __restrict__ ctxW,
    const float* __restrict__ tuneW, __half* __restrict__ h_hist) {
  extern __shared__ uint32_t smem[];
  uint32_t* Ulds   = smem;
  float*    zpart  = (float*)(smem + OFF_ZPART);
  float*    ctxlds = (float*)(smem + OFF_CTX);
  uint32_t* hbuf   = smem + OFF_HBUF;
  int*      tlds   = (int*)(smem + OFF_TLDS);

  int b    = blockIdx.x;
  int tid  = threadIdx.x;
  int g    = tid >> 8;        // K-group
  int q    = tid & 255;       // column-owner index within group
  int lane = tid & 63;
  int L    = tlen[b];

  for (int i = tid; i < TT; i += NT) tlds[i] = tune[b*TT + i];
  for (int i = tid; i < G4; i += NT) ctxlds[i] = ctxW[b*G4 + i];
  if (tid < 128) hbuf[tid] = 0u;
  for (int idx = tid; idx < ULDS_ROWS*G4; idx += NT) {
    int row = idx >> 10, j = idx & 1023;
    int gg = row / KLDS, r = row % KLDS;
    Ulds[idx] = Up[(gg*64 + KREG + r)*G4 + j];
  }

  uint4 ureg[KREG];
  {
    const uint32_t* ubase = Up + (size_t)(g*64)*G4 + 4*q;
#pragma unroll
    for (int kk = 0; kk < KREG; kk++) ureg[kk] = *(const uint4*)(ubase + (size_t)kk*G4);
  }
  float cc = 0.f;
  __syncthreads();

  const uint32_t* uldsrow = Ulds + (size_t)(g*KLDS)*G4 + 4*q;
  __half* hh_base = h_hist + (size_t)b*TT*HH;

  for (int t = 0; t < L; t++) {
    uint32_t vh = hbuf[g*64 + lane];   // lane-spread read of this group's h slice
    int v = tlds[t];
    float tw0, tw1, tw2, tw3;
    if (tid < HH) {                    // prefetch tuneW row slices for epilogue
      const float* twp = tuneW + (size_t)v*G4 + tid;
      tw0 = twp[0]; tw1 = twp[256]; tw2 = twp[512]; tw3 = twp[768];
    }
    float a0 = 0.f, a1 = 0.f, a2 = 0.f, a3 = 0.f;
#pragma unroll
    for (int kk = 0; kk < KREG; kk++) {
      uint32_t hs = (uint32_t)__builtin_amdgcn_readlane((int)vh, kk);
      a0 = fdot2(hs, ureg[kk].x, a0);
      a1 = fdot2(hs, ureg[kk].y, a1);
      a2 = fdot2(hs, ureg[kk].z, a2);
      a3 = fdot2(hs, ureg[kk].w, a3);
    }
#pragma unroll
    for (int r = 0; r < KLDS; r++) {
      uint4 ul = *(const uint4*)(uldsrow + (size_t)r*G4);
      uint32_t hs = (uint32_t)__builtin_amdgcn_readlane((int)vh, KREG + r);
      a0 = fdot2(hs, ul.x, a0);
      a1 = fdot2(hs, ul.y, a1);
      a2 = fdot2(hs, ul.z, a2);
      a3 = fdot2(hs, ul.w, a3);
    }
    *(float4*)(zpart + g*G4 + 4*q) = make_float4(a0, a1, a2, a3);
    __syncthreads();
    if (tid < HH) {
      float zi = zpart[tid      ] + zpart[G4 + tid      ] + ctxlds[tid      ] + tw0;
      float zf = zpart[tid + 256] + zpart[G4 + tid + 256] + ctxlds[tid + 256] + tw1;
      float zg = zpart[tid + 512] + zpart[G4 + tid + 512] + ctxlds[tid + 512] + tw2;
      float zo = zpart[tid + 768] + zpart[G4 + tid + 768] + ctxlds[tid + 768] + tw3;
      float gi = 1.f / (1.f + __expf(-zi));
      float gf = 1.f / (1.f + __expf(-zf));
      float e2 = __expf(2.f*zg);
      float gg = (e2 - 1.f) / (e2 + 1.f);
      float go = 1.f / (1.f + __expf(-zo));
      cc = gf*cc + gi*gg;
      float ec = __expf(2.f*cc);
      float th = (ec - 1.f) / (ec + 1.f);
      float hv = go * th;
      __half hhv = __float2half(hv);
      ((__half*)hbuf)[tid] = hhv;
      hh_base[(size_t)t*HH + tid] = hhv;   // fire-and-forget history store
    }
    __syncthreads();
  }
}

// ---------------- output projection ----------------
// out[b,t,:] = h[b,t,:] @ Wd + bd  (t < L), else bd.
// h history lives (f16-packed) in d_out itself; each block stages its A-tile to
// LDS before overwriting exactly those rows -> no race (rows are block-private).

__global__ __launch_bounds__(256) void out_gemm_k(
    const uint32_t* __restrict__ hsrc, const uint32_t* __restrict__ Wdp,
    const float* __restrict__ bd, const int* __restrict__ tlen,
    float* __restrict__ out) {
  __shared__ uint32_t A[64][128];   // 32KB: 64 rows x 128 packed f16-pairs
  int bb = blockIdx.x;
  int b  = bb >> 3, t0 = (bb & 7) << 6;
  int tid = threadIdx.x;
  int L = tlen[b];
  for (int idx = tid; idx < 64*128; idx += 256) {
    int r = idx >> 7, kp = idx & 127;
    int t = t0 + r;
    A[r][kp] = (t < TT) ? hsrc[((size_t)b*TT + t)*128 + kp] : 0u;
  }
  __syncthreads();
  int v = tid & 127, rg = tid >> 7;
  float acc[32];
#pragma unroll
  for (int r = 0; r < 32; r++) acc[r] = 0.f;
  for (int kb = 0; kb < 4; kb++) {
    uint32_t w[32];
#pragma unroll
    for (int q = 0; q < 32; q++) w[q] = Wdp[(kb*32+q)*VV + v];
#pragma unroll
    for (int r = 0; r < 32; r++) {
      const uint32_t* ar = &A[rg*32 + r][kb*32];
#pragma unroll
      for (int q4 = 0; q4 < 8; q4++) {
        uint4 a4 = *(const uint4*)(ar + q4*4);   // wave-uniform -> broadcast
        acc[r] = fdot2(a4.x, w[4*q4+0], acc[r]);
        acc[r] = fdot2(a4.y, w[4*q4+1], acc[r]);
        acc[r] = fdot2(a4.z, w[4*q4+2], acc[r]);
        acc[r] = fdot2(a4.w, w[4*q4+3], acc[r]);
      }
    }
  }
  float bias = bd[v];
#pragma unroll
  for (int r = 0; r < 32; r++) {
    int t = t0 + rg*32 + r;
    if (t < TT) {
      out[((size_t)b*TT + t)*VV + v] = (t < L) ? (acc[r] + bias) : bias;
    }
  }
}

// ---------------- launch ----------------

extern "C" void kernel_launch(void* const* d_in, const int* in_sizes, int n_in,
                              void* d_out, int out_size, void* d_ws, size_t ws_size,
                              hipStream_t stream) {
  const int*   tune   = (const int*)d_in[0];
  const int*   rhythm = (const int*)d_in[1];
  const int*   meter  = (const int*)d_in[2];
  const int*   keyi   = (const int*)d_in[3];
  const int*   tlen   = (const int*)d_in[4];
  const float* er     = (const float*)d_in[5];
  const float* em     = (const float*)d_in[6];
  const float* ek     = (const float*)d_in[7];
  const float* et     = (const float*)d_in[8];
  const float* W      = (const float*)d_in[9];
  const float* U      = (const float*)d_in[10];
  const float* bias   = (const float*)d_in[11];
  const float* Wd     = (const float*)d_in[12];
  const float* bd     = (const float*)d_in[13];
  (void)in_sizes; (void)n_in; (void)out_size; (void)ws_size;

  char* ws = (char*)d_ws;
  uint32_t* Up    = (uint32_t*)(ws);                                      // 512KB
  float*    ctxW  = (float*)(ws + (512<<10));                             // 1MB
  float*    tuneW = (float*)(ws + (512<<10) + (1024<<10));                // 516KB
  uint32_t* Wdp   = (uint32_t*)(ws + (512<<10) + (1024<<10) + (516<<10)); // 64KB

  hipFuncSetAttribute((const void*)lstm_rec_k,
                      hipFuncAttributeMaxDynamicSharedMemorySize, SMEM_BYTES);

  prep_ctx_k <<<BB,    1024, 0, stream>>>(rhythm, meter, keyi, er, em, ek, W, bias, ctxW);
  prep_tune_k<<<VV+1,  1024, 0, stream>>>(et, W, tuneW);
  prep_U_k   <<<128,   1024, 0, stream>>>(U, Up);
  prep_Wd_k  <<<128,   VV,   0, stream>>>(Wd, Wdp);
  lstm_rec_k <<<BB, NT, SMEM_BYTES, stream>>>(tune, tlen, Up, ctxW, tuneW, (__half*)d_out);
  out_gemm_k <<<BB*8,  256,  0, stream>>>((const uint32_t*)d_out, Wdp, bd, tlen, (float*)d_out);
}